// Round 1
// baseline (3189.298 us; speedup 1.0000x reference)
//
#include <hip/hip_runtime.h>

#define N_NODES 50000
#define N_EDGES 800000
#define DIM 128
#define NUM_GRAPHS 128

// ---------------- degree / norm precompute ----------------

__global__ __launch_bounds__(256) void k_init_deg(float* deg, int n) {
    int i = blockIdx.x * 256 + threadIdx.x;
    if (i < n) deg[i] = 1.0f;  // self-loop weight
}

__global__ __launch_bounds__(256) void k_deg_accum(const int* __restrict__ dst,
                                                   const float* __restrict__ attr,
                                                   float* deg, int E) {
    int e = blockIdx.x * 256 + threadIdx.x;
    if (e < E) atomicAdd(&deg[dst[e]], attr[e]);
}

__global__ __launch_bounds__(256) void k_dinv(float* deg, int n) {
    int i = blockIdx.x * 256 + threadIdx.x;
    if (i < n) {
        float d0 = deg[i];
        deg[i] = d0 > 0.f ? rsqrtf(fmaxf(d0, 1e-12f)) : 0.f;
    }
}

__global__ __launch_bounds__(256) void k_norm(const int* __restrict__ src,
                                              const int* __restrict__ dst,
                                              const float* __restrict__ attr,
                                              const float* __restrict__ dinv,
                                              float* __restrict__ norm, int E) {
    int e = blockIdx.x * 256 + threadIdx.x;
    if (e < E) norm[e] = dinv[src[e]] * attr[e] * dinv[dst[e]];
}

// ---------------- GEMM (N x 128) @ (128 x 128), fp32, W in LDS ----------------
// Fused epilogue: H = A@W, AGG = dinv[row]^2 * H  (self-loop init for scatter).
// NOTE: A and AGG may alias (layer 2). Safe: each row is read only by lanes of
// the same half-wave that writes it, and all k-loop loads precede the stores in
// the single wave instruction stream. So no __restrict__ on A / AGG.

__global__ __launch_bounds__(256) void k_gemm_selfinit(const float* A,
                                                       const float* __restrict__ W,
                                                       const float* __restrict__ dinv,
                                                       float* __restrict__ H,
                                                       float* AGG, int n) {
    __shared__ float4 sW[128 * 32];  // 128 rows(k) x 128 cols, as float4 = 64 KB
    int tid = threadIdx.x;
    const float4* W4 = (const float4*)W;
#pragma unroll
    for (int i = 0; i < 16; i++) sW[tid + i * 256] = W4[tid + i * 256];
    __syncthreads();

    int tx = tid & 31;       // column group: cols 4*tx .. 4*tx+3
    int ty = tid >> 5;       // 8 row groups of 4 rows
    int row0 = blockIdx.x * 32 + ty * 4;

    const float4* Ar[4];
#pragma unroll
    for (int r = 0; r < 4; r++) {
        int rr = row0 + r;
        if (rr >= n) rr = n - 1;  // clamp for loads; stores guarded
        Ar[r] = (const float4*)(A + (size_t)rr * DIM);
    }

    float4 acc[4];
#pragma unroll
    for (int r = 0; r < 4; r++) acc[r] = make_float4(0.f, 0.f, 0.f, 0.f);

    for (int k4 = 0; k4 < 32; k4++) {
        float4 w0 = sW[(4 * k4 + 0) * 32 + tx];
        float4 w1 = sW[(4 * k4 + 1) * 32 + tx];
        float4 w2 = sW[(4 * k4 + 2) * 32 + tx];
        float4 w3 = sW[(4 * k4 + 3) * 32 + tx];
#pragma unroll
        for (int r = 0; r < 4; r++) {
            float4 a = Ar[r][k4];
            acc[r].x += a.x * w0.x + a.y * w1.x + a.z * w2.x + a.w * w3.x;
            acc[r].y += a.x * w0.y + a.y * w1.y + a.z * w2.y + a.w * w3.y;
            acc[r].z += a.x * w0.z + a.y * w1.z + a.z * w2.z + a.w * w3.z;
            acc[r].w += a.x * w0.w + a.y * w1.w + a.z * w2.w + a.w * w3.w;
        }
    }

#pragma unroll
    for (int r = 0; r < 4; r++) {
        int rr = row0 + r;
        if (rr < n) {
            float di = dinv[rr];
            float sw = di * di;
            ((float4*)(H + (size_t)rr * DIM))[tx] = acc[r];
            float4 ag = make_float4(sw * acc[r].x, sw * acc[r].y,
                                    sw * acc[r].z, sw * acc[r].w);
            ((float4*)(AGG + (size_t)rr * DIM))[tx] = ag;
        }
    }
}

// ---------------- edge scatter: agg[dst] += norm_e * h[src] ----------------
// 32 lanes per edge, float4 per lane.

__global__ __launch_bounds__(256) void k_edge_scatter(const int* __restrict__ src,
                                                      const int* __restrict__ dst,
                                                      const float* __restrict__ norm,
                                                      const float* __restrict__ h,
                                                      float* agg, int E) {
    int t = blockIdx.x * 256 + threadIdx.x;
    int e = t >> 5;
    int lane = t & 31;
    if (e >= E) return;
    int s = src[e];
    int d = dst[e];
    float w = norm[e];
    float4 v = ((const float4*)(h + (size_t)s * DIM))[lane];
    float* o = agg + (size_t)d * DIM + lane * 4;
    atomicAdd(o + 0, w * v.x);
    atomicAdd(o + 1, w * v.y);
    atomicAdd(o + 2, w * v.z);
    atomicAdd(o + 3, w * v.w);
}

// ---------------- bias + relu (in place) ----------------

__global__ __launch_bounds__(256) void k_bias_relu(float* X, const float* __restrict__ b, int n) {
    int idx = blockIdx.x * 256 + threadIdx.x;
    int i = idx >> 5;
    int lane = idx & 31;
    if (i >= n) return;
    float4 bb = ((const float4*)b)[lane];
    float4* p = (float4*)(X + (size_t)i * DIM) + lane;
    float4 v = *p;
    v.x = fmaxf(v.x + bb.x, 0.f);
    v.y = fmaxf(v.y + bb.y, 0.f);
    v.z = fmaxf(v.z + bb.z, 0.f);
    v.w = fmaxf(v.w + bb.w, 0.f);
    *p = v;
}

// ---------------- pooling ----------------

__global__ __launch_bounds__(256) void k_zero(float* p, int n) {
    int i = blockIdx.x * 256 + threadIdx.x;
    if (i < n) p[i] = 0.f;
}

__global__ __launch_bounds__(256) void k_pool(const float* __restrict__ X,
                                              const int* __restrict__ batch,
                                              float* gsum, float* cnt, int n) {
    int idx = blockIdx.x * 256 + threadIdx.x;
    int i = idx >> 5;
    int lane = idx & 31;
    if (i >= n) return;
    int g = batch[i];
    float4 v = ((const float4*)(X + (size_t)i * DIM))[lane];
    float* o = gsum + (size_t)g * DIM + lane * 4;
    atomicAdd(o + 0, v.x);
    atomicAdd(o + 1, v.y);
    atomicAdd(o + 2, v.z);
    atomicAdd(o + 3, v.w);
    if (lane == 0) atomicAdd(&cnt[g], 1.0f);
}

// ---------------- classifier: relu(g@Wc1+bc1)@Wc2+bc2 ----------------

__global__ __launch_bounds__(128) void k_classifier(const float* __restrict__ gsum,
                                                    const float* __restrict__ cnt,
                                                    const float* __restrict__ Wc1,
                                                    const float* __restrict__ bc1,
                                                    const float* __restrict__ Wc2,
                                                    const float* __restrict__ bc2,
                                                    float* __restrict__ out) {
    int g = blockIdx.x;
    int t = threadIdx.x;  // 128
    __shared__ float gv[128];
    __shared__ float hid[128];
    float inv = 1.0f / fmaxf(cnt[g], 1.0f);
    gv[t] = gsum[(size_t)g * DIM + t] * inv;
    __syncthreads();
    float acc = bc1[t];
    for (int k = 0; k < 128; k++) acc += gv[k] * Wc1[k * 128 + t];
    hid[t] = fmaxf(acc, 0.f);
    __syncthreads();
    if (t < 4) {
        float o = bc2[t];
        for (int k = 0; k < 128; k++) o += hid[k] * Wc2[k * 4 + t];
        out[g * 4 + t] = o;
    }
}

// ---------------- launch ----------------

extern "C" void kernel_launch(void* const* d_in, const int* in_sizes, int n_in,
                              void* d_out, int out_size, void* d_ws, size_t ws_size,
                              hipStream_t stream) {
    const float* x    = (const float*)d_in[0];
    const int*   ei   = (const int*)d_in[1];     // [2, E]: src then dst
    const float* attr = (const float*)d_in[2];
    // d_in[3] edge_weight: unused by reference
    const int*   batch = (const int*)d_in[4];
    const float* W0  = (const float*)d_in[5];
    const float* b0  = (const float*)d_in[6];
    const float* W1  = (const float*)d_in[7];
    const float* b1  = (const float*)d_in[8];
    const float* Wc1 = (const float*)d_in[9];
    const float* bc1 = (const float*)d_in[10];
    const float* Wc2 = (const float*)d_in[11];
    const float* bc2 = (const float*)d_in[12];
    float* out = (float*)d_out;

    char* ws = (char*)d_ws;
    float* dinv = (float*)(ws + 0);          //   200,000 B
    float* norm = (float*)(ws + 200000);     // 3,200,000 B
    float* bufH = (float*)(ws + 3400000);    // 25,600,000 B (h)
    float* bufA = (float*)(ws + 29000000);   // 25,600,000 B (agg)
    float* gsum = (float*)(ws + 54600000);   // 65,536 B
    float* cnt  = gsum + NUM_GRAPHS * DIM;   // 512 B
    const int* src = ei;
    const int* dst = ei + N_EDGES;

    // normalization precompute (shared by both layers)
    k_init_deg<<<(N_NODES + 255) / 256, 256, 0, stream>>>(dinv, N_NODES);
    k_deg_accum<<<(N_EDGES + 255) / 256, 256, 0, stream>>>(dst, attr, dinv, N_EDGES);
    k_dinv<<<(N_NODES + 255) / 256, 256, 0, stream>>>(dinv, N_NODES);
    k_norm<<<(N_EDGES + 255) / 256, 256, 0, stream>>>(src, dst, attr, dinv, norm, N_EDGES);

    // layer 1
    k_gemm_selfinit<<<(N_NODES + 31) / 32, 256, 0, stream>>>(x, W0, dinv, bufH, bufA, N_NODES);
    k_edge_scatter<<<(N_EDGES * 32) / 256, 256, 0, stream>>>(src, dst, norm, bufH, bufA, N_EDGES);
    k_bias_relu<<<(N_NODES * 32 + 255) / 256, 256, 0, stream>>>(bufA, b0, N_NODES);

    // layer 2 (A aliases AGG inside gemm — safe per half-wave row ownership)
    k_gemm_selfinit<<<(N_NODES + 31) / 32, 256, 0, stream>>>(bufA, W1, dinv, bufH, bufA, N_NODES);
    k_edge_scatter<<<(N_EDGES * 32) / 256, 256, 0, stream>>>(src, dst, norm, bufH, bufA, N_EDGES);
    k_bias_relu<<<(N_NODES * 32 + 255) / 256, 256, 0, stream>>>(bufA, b1, N_NODES);

    // global mean pool + classifier
    k_zero<<<(NUM_GRAPHS * DIM + NUM_GRAPHS + 255) / 256, 256, 0, stream>>>(gsum, NUM_GRAPHS * DIM + NUM_GRAPHS);
    k_pool<<<(N_NODES * 32) / 256, 256, 0, stream>>>(bufA, batch, gsum, cnt, N_NODES);
    k_classifier<<<NUM_GRAPHS, 128, 0, stream>>>(gsum, cnt, Wc1, bc1, Wc2, bc2, out);
}

// Round 2
// 692.653 us; speedup vs baseline: 4.6045x; 4.6045x over previous
//
#include <hip/hip_runtime.h>

#define N_NODES 50000
#define N_EDGES 800000
#define DIM 128
#define NUM_GRAPHS 128

// ================= degree / dinv precompute =================

__global__ __launch_bounds__(256) void k_init_deg(float* deg, int n) {
    int i = blockIdx.x * 256 + threadIdx.x;
    if (i < n) deg[i] = 1.0f;  // self-loop weight
}

__global__ __launch_bounds__(256) void k_deg_accum(const int* __restrict__ dst,
                                                   const float* __restrict__ attr,
                                                   float* deg, int E) {
    int e = blockIdx.x * 256 + threadIdx.x;
    if (e < E) atomicAdd(&deg[dst[e]], attr[e]);
}

__global__ __launch_bounds__(256) void k_dinv(float* deg, int n) {
    int i = blockIdx.x * 256 + threadIdx.x;
    if (i < n) {
        float d0 = deg[i];
        deg[i] = d0 > 0.f ? rsqrtf(fmaxf(d0, 1e-12f)) : 0.f;
    }
}

// ================= CSR build (sort edges by dst, on device, every call) ====

__global__ __launch_bounds__(256) void k_zero_int(int* p, int n) {
    int i = blockIdx.x * 256 + threadIdx.x;
    if (i < n) p[i] = 0;
}

__global__ __launch_bounds__(256) void k_hist(const int* __restrict__ dst, int* counts, int E) {
    int e = blockIdx.x * 256 + threadIdx.x;
    if (e < E) atomicAdd(&counts[dst[e]], 1);
}

// 3-kernel exclusive scan over counts[n] -> offs[n]; partials has >= gridDim ints
__global__ __launch_bounds__(256) void k_scan1(const int* __restrict__ counts,
                                               int* __restrict__ offs,
                                               int* __restrict__ partials, int n) {
    __shared__ int tmp[256];
    int t = threadIdx.x;
    int gid = blockIdx.x * 256 + t;
    int v = gid < n ? counts[gid] : 0;
    tmp[t] = v;
    __syncthreads();
    for (int off = 1; off < 256; off <<= 1) {
        int add = (t >= off) ? tmp[t - off] : 0;
        __syncthreads();
        tmp[t] += add;
        __syncthreads();
    }
    if (gid < n) offs[gid] = tmp[t] - v;  // exclusive within block
    if (t == 255) partials[blockIdx.x] = tmp[255];
}

__global__ __launch_bounds__(256) void k_scan2(int* partials, int nb) {  // nb <= 256, 1 block
    __shared__ int tmp[256];
    int t = threadIdx.x;
    int v = t < nb ? partials[t] : 0;
    tmp[t] = v;
    __syncthreads();
    for (int off = 1; off < 256; off <<= 1) {
        int add = (t >= off) ? tmp[t - off] : 0;
        __syncthreads();
        tmp[t] += add;
        __syncthreads();
    }
    if (t < nb) partials[t] = tmp[t] - v;  // exclusive
}

__global__ __launch_bounds__(256) void k_scan3(int* __restrict__ offs,
                                               const int* __restrict__ partials, int n) {
    int gid = blockIdx.x * 256 + threadIdx.x;
    if (gid < n) offs[gid] += partials[blockIdx.x];
}

// scatter edges to dst-sorted arrays; also computes norm inline
__global__ __launch_bounds__(256) void k_scatter_edges(const int* __restrict__ src,
                                                       const int* __restrict__ dst,
                                                       const float* __restrict__ attr,
                                                       const float* __restrict__ dinv,
                                                       const int* __restrict__ offs,
                                                       int* cur,
                                                       unsigned short* __restrict__ src_s,
                                                       float* __restrict__ nrm_s, int E) {
    int e = blockIdx.x * 256 + threadIdx.x;
    if (e >= E) return;
    int s = src[e];
    int d = dst[e];
    int p = offs[d] + atomicAdd(&cur[d], 1);
    src_s[p] = (unsigned short)s;
    nrm_s[p] = dinv[s] * attr[e] * dinv[d];
}

// ================= GEMM (N x 128) @ (128 x 128), fp32, W in LDS ============

__global__ __launch_bounds__(256) void k_gemm(const float* __restrict__ A,
                                              const float* __restrict__ W,
                                              float* __restrict__ H, int n) {
    __shared__ float4 sW[128 * 32];  // 128 rows(k) x 128 cols, as float4 = 64 KB
    int tid = threadIdx.x;
    const float4* W4 = (const float4*)W;
#pragma unroll
    for (int i = 0; i < 16; i++) sW[tid + i * 256] = W4[tid + i * 256];
    __syncthreads();

    int tx = tid & 31;   // cols 4*tx .. 4*tx+3
    int ty = tid >> 5;   // 8 row groups of 4 rows
    int row0 = blockIdx.x * 32 + ty * 4;

    const float4* Ar[4];
#pragma unroll
    for (int r = 0; r < 4; r++) {
        int rr = row0 + r;
        if (rr >= n) rr = n - 1;  // clamp for loads; stores guarded
        Ar[r] = (const float4*)(A + (size_t)rr * DIM);
    }

    float4 acc[4];
#pragma unroll
    for (int r = 0; r < 4; r++) acc[r] = make_float4(0.f, 0.f, 0.f, 0.f);

    for (int k4 = 0; k4 < 32; k4++) {
        float4 w0 = sW[(4 * k4 + 0) * 32 + tx];
        float4 w1 = sW[(4 * k4 + 1) * 32 + tx];
        float4 w2 = sW[(4 * k4 + 2) * 32 + tx];
        float4 w3 = sW[(4 * k4 + 3) * 32 + tx];
#pragma unroll
        for (int r = 0; r < 4; r++) {
            float4 a = Ar[r][k4];
            acc[r].x += a.x * w0.x + a.y * w1.x + a.z * w2.x + a.w * w3.x;
            acc[r].y += a.x * w0.y + a.y * w1.y + a.z * w2.y + a.w * w3.y;
            acc[r].z += a.x * w0.z + a.y * w1.z + a.z * w2.z + a.w * w3.z;
            acc[r].w += a.x * w0.w + a.y * w1.w + a.z * w2.w + a.w * w3.w;
        }
    }

#pragma unroll
    for (int r = 0; r < 4; r++) {
        int rr = row0 + r;
        if (rr < n) ((float4*)(H + (size_t)rr * DIM))[tx] = acc[r];
    }
}

// ================= CSR gather: out[d] = relu(bias + dinv[d]^2 h[d] + sum nrm*h[src]) ==
// 32 lanes per node (float4 each). POOL variant fuses mean-pool accumulation.

template <bool POOL>
__global__ __launch_bounds__(256) void k_gather(const float* __restrict__ H,
                                                const int* __restrict__ offs,
                                                const unsigned short* __restrict__ srcs,
                                                const float* __restrict__ nrm,
                                                const float* __restrict__ dinv,
                                                const float* __restrict__ bias,
                                                const int* __restrict__ batch,
                                                float* __restrict__ OUT,
                                                float* gsum, float* cnt, int n) {
    int idx = blockIdx.x * 256 + threadIdx.x;
    int i = idx >> 5;
    int lane = idx & 31;
    if (i >= n) return;
    const float4* H4 = (const float4*)H;

    float di = dinv[i];
    float sw = di * di;
    float4 self = H4[(size_t)i * 32 + lane];
    float4 acc = make_float4(sw * self.x, sw * self.y, sw * self.z, sw * self.w);

    int j = offs[i];
    int end = (i == n - 1) ? N_EDGES : offs[i + 1];
    // 2-deep to keep two h-row loads in flight
    for (; j + 1 < end; j += 2) {
        int s0 = srcs[j];
        int s1 = srcs[j + 1];
        float w0 = nrm[j];
        float w1 = nrm[j + 1];
        float4 v0 = H4[(size_t)s0 * 32 + lane];
        float4 v1 = H4[(size_t)s1 * 32 + lane];
        acc.x += w0 * v0.x + w1 * v1.x;
        acc.y += w0 * v0.y + w1 * v1.y;
        acc.z += w0 * v0.z + w1 * v1.z;
        acc.w += w0 * v0.w + w1 * v1.w;
    }
    if (j < end) {
        int s0 = srcs[j];
        float w0 = nrm[j];
        float4 v0 = H4[(size_t)s0 * 32 + lane];
        acc.x += w0 * v0.x;
        acc.y += w0 * v0.y;
        acc.z += w0 * v0.z;
        acc.w += w0 * v0.w;
    }

    float4 bb = ((const float4*)bias)[lane];
    acc.x = fmaxf(acc.x + bb.x, 0.f);
    acc.y = fmaxf(acc.y + bb.y, 0.f);
    acc.z = fmaxf(acc.z + bb.z, 0.f);
    acc.w = fmaxf(acc.w + bb.w, 0.f);

    if (POOL) {
        int g = batch[i];
        float* o = gsum + (size_t)g * DIM + lane * 4;
        atomicAdd(o + 0, acc.x);
        atomicAdd(o + 1, acc.y);
        atomicAdd(o + 2, acc.z);
        atomicAdd(o + 3, acc.w);
        if (lane == 0) atomicAdd(&cnt[g], 1.0f);
    } else {
        ((float4*)OUT)[(size_t)i * 32 + lane] = acc;
    }
}

// ================= pooling scratch zero + classifier =================

__global__ __launch_bounds__(256) void k_zero(float* p, int n) {
    int i = blockIdx.x * 256 + threadIdx.x;
    if (i < n) p[i] = 0.f;
}

__global__ __launch_bounds__(128) void k_classifier(const float* __restrict__ gsum,
                                                    const float* __restrict__ cnt,
                                                    const float* __restrict__ Wc1,
                                                    const float* __restrict__ bc1,
                                                    const float* __restrict__ Wc2,
                                                    const float* __restrict__ bc2,
                                                    float* __restrict__ out) {
    int g = blockIdx.x;
    int t = threadIdx.x;  // 128
    __shared__ float gv[128];
    __shared__ float hid[128];
    float inv = 1.0f / fmaxf(cnt[g], 1.0f);
    gv[t] = gsum[(size_t)g * DIM + t] * inv;
    __syncthreads();
    float acc = bc1[t];
    for (int k = 0; k < 128; k++) acc += gv[k] * Wc1[k * 128 + t];
    hid[t] = fmaxf(acc, 0.f);
    __syncthreads();
    if (t < 4) {
        float o = bc2[t];
        for (int k = 0; k < 128; k++) o += hid[k] * Wc2[k * 4 + t];
        out[g * 4 + t] = o;
    }
}

// ================= launch =================

extern "C" void kernel_launch(void* const* d_in, const int* in_sizes, int n_in,
                              void* d_out, int out_size, void* d_ws, size_t ws_size,
                              hipStream_t stream) {
    const float* x     = (const float*)d_in[0];
    const int*   ei    = (const int*)d_in[1];  // [2, E]: src then dst
    const float* attr  = (const float*)d_in[2];
    // d_in[3] edge_weight: unused by reference
    const int*   batch = (const int*)d_in[4];
    const float* W0  = (const float*)d_in[5];
    const float* b0  = (const float*)d_in[6];
    const float* W1  = (const float*)d_in[7];
    const float* b1  = (const float*)d_in[8];
    const float* Wc1 = (const float*)d_in[9];
    const float* bc1 = (const float*)d_in[10];
    const float* Wc2 = (const float*)d_in[11];
    const float* bc2 = (const float*)d_in[12];
    float* out = (float*)d_out;

    char* ws = (char*)d_ws;
    float*          bufH     = (float*)(ws + 0);           // 25,600,000
    float*          bufA     = (float*)(ws + 25600000);    // 25,600,000
    float*          nrm_s    = (float*)(ws + 51200000);    //  3,200,000
    unsigned short* src_s    = (unsigned short*)(ws + 54400000);  // 1,600,000
    float*          dinv     = (float*)(ws + 56000000);    //    200,000
    int*            offs     = (int*)(ws + 56200000);      //    200,064
    int*            counts   = (int*)(ws + 56400064);      //    200,000 (also cursor)
    int*            partials = (int*)(ws + 56600064);      //      1,024
    float*          gsum     = (float*)(ws + 56601088);    //     65,536
    float*          cnt      = (float*)(ws + 56666624);    //        512

    const int* src = ei;
    const int* dst = ei + N_EDGES;

    const int NB_N = (N_NODES + 255) / 256;   // 196
    const int NB_E = (N_EDGES + 255) / 256;   // 3125

    // dinv = rsqrt(1 + sum attr over in-edges)
    k_init_deg<<<NB_N, 256, 0, stream>>>(dinv, N_NODES);
    k_deg_accum<<<NB_E, 256, 0, stream>>>(dst, attr, dinv, N_EDGES);
    k_dinv<<<NB_N, 256, 0, stream>>>(dinv, N_NODES);

    // CSR build: counts -> exclusive scan -> scatter sorted (src, norm)
    k_zero_int<<<NB_N, 256, 0, stream>>>(counts, N_NODES);
    k_hist<<<NB_E, 256, 0, stream>>>(dst, counts, N_EDGES);
    k_scan1<<<NB_N, 256, 0, stream>>>(counts, offs, partials, N_NODES);
    k_scan2<<<1, 256, 0, stream>>>(partials, NB_N);
    k_scan3<<<NB_N, 256, 0, stream>>>(offs, partials, N_NODES);
    k_zero_int<<<NB_N, 256, 0, stream>>>(counts, N_NODES);  // reuse as cursor
    k_scatter_edges<<<NB_E, 256, 0, stream>>>(src, dst, attr, dinv, offs, counts,
                                              src_s, nrm_s, N_EDGES);

    // zero pool accumulators (ws is poisoned 0xAA each call)
    k_zero<<<(NUM_GRAPHS * DIM + NUM_GRAPHS + 255) / 256, 256, 0, stream>>>(
        gsum, NUM_GRAPHS * DIM + NUM_GRAPHS);

    const int NB_G = (N_NODES * 32 + 255) / 256;  // 6250

    // layer 1: gemm + gather(bias+relu fused)
    k_gemm<<<(N_NODES + 31) / 32, 256, 0, stream>>>(x, W0, bufH, N_NODES);
    k_gather<false><<<NB_G, 256, 0, stream>>>(bufH, offs, src_s, nrm_s, dinv, b0,
                                              batch, bufA, gsum, cnt, N_NODES);

    // layer 2: gemm + gather(bias+relu+mean-pool fused; no h2 materialization)
    k_gemm<<<(N_NODES + 31) / 32, 256, 0, stream>>>(bufA, W1, bufH, N_NODES);
    k_gather<true><<<NB_G, 256, 0, stream>>>(bufH, offs, src_s, nrm_s, dinv, b1,
                                             batch, nullptr, gsum, cnt, N_NODES);

    // classifier
    k_classifier<<<NUM_GRAPHS, 128, 0, stream>>>(gsum, cnt, Wc1, bc1, Wc2, bc2, out);
}